// Round 4
// baseline (18.469 us; speedup 1.0000x reference)
//
#include <hip/hip_runtime.h>

// out[k] = (sum_j sigmoid(s*(x[j]-x[k])) + 0.5) / N,  s = SCALE/std(triu diff matrix)
// std closed form: var = (N*sum(x^2) - sum(x)^2 - S^2/N^2) / (N^2-1),
//                  S = sum_k x[k]*(2k - N + 1)
//
// R3: occupancy push. 512-thread blocks (8 waves), j-split 8-way ->
// 8 waves/SIMD (max). Prologue trimmed: row staged in LDS already scaled
// (raw row lives in registers through the stats phase), one barrier fewer.
// Inner loop: quad-batched rcp (1 v_rcp per 4 elems), clamp keeps products
// finite (sigma trunc err <= 2.4e-4, threshold is 2e-2).

constexpr int   N      = 1024;
constexpr int   KPB    = 64;          // outputs per block
constexpr int   WAVES  = 8;
constexpr int   JCHUNK = N / WAVES;   // 128 j's per wave
constexpr float SCALE  = 6.8f;
constexpr float LOG2E  = 1.4426950408889634f;

__device__ __forceinline__ float quadSig(float cxk, float4 xj)
{
    // t_i = 2^(cxk - c*x_j), sigmoid in log2 domain (xj pre-scaled by c)
    float t0 = __builtin_amdgcn_exp2f(cxk - xj.x);
    float t1 = __builtin_amdgcn_exp2f(cxk - xj.y);
    float t2 = __builtin_amdgcn_exp2f(cxk - xj.z);
    float t3 = __builtin_amdgcn_exp2f(cxk - xj.w);
    t0 = fminf(t0, 4096.0f);
    t1 = fminf(t1, 4096.0f);
    t2 = fminf(t2, 4096.0f);
    t3 = fminf(t3, 4096.0f);
    const float a = t0 + 1.0f, b = t1 + 1.0f;
    const float c = t2 + 1.0f, d = t3 + 1.0f;
    const float ab  = a * b;
    const float cd  = c * d;
    const float num = (a + b) * cd + (c + d) * ab;   // 1/a+1/b+1/c+1/d = num/(ab*cd)
    return num * __builtin_amdgcn_rcpf(ab * cd);
}

__global__ __launch_bounds__(512) void softrank_kernel(
    const float* __restrict__ in, float* __restrict__ out)
{
    const int row  = blockIdx.y;
    const int tid  = threadIdx.x;
    const int lane = tid & 63;
    const int wave = tid >> 6;

    __shared__ float xs[N];           // row scaled by c = s*log2(e)
    __shared__ float wred[WAVES][3];
    __shared__ float part[WAVES][KPB];

    const float* x = in + row * N;

    // 512 threads x float2 = 1024 elems; raw values stay in registers
    const float2 v = reinterpret_cast<const float2*>(x)[tid];

    // O(N) stats partials
    const int k0 = tid * 2;
    float psum = v.x + v.y;
    float psq  = v.x * v.x + v.y * v.y;
    float pw   = v.x * (float)(2 * k0       - (N - 1))
               + v.y * (float)(2 * (k0 + 1) - (N - 1));

    #pragma unroll
    for (int off = 32; off >= 1; off >>= 1) {
        psum += __shfl_down(psum, off, 64);
        psq  += __shfl_down(psq,  off, 64);
        pw   += __shfl_down(pw,   off, 64);
    }
    if (lane == 0) {
        wred[wave][0] = psum;
        wred[wave][1] = psq;
        wred[wave][2] = pw;
    }
    __syncthreads();

    float sum = 0.f, sq = 0.f, sw = 0.f;
    #pragma unroll
    for (int w = 0; w < WAVES; ++w) {
        sum += wred[w][0];
        sq  += wred[w][1];
        sw  += wred[w][2];
    }

    const float n2     = (float)N * (float)N;
    const float pairSq = (float)N * sq - sum * sum;
    const float var    = (pairSq - (sw * sw) / n2) / (n2 - 1.0f);
    const float s      = SCALE * __builtin_amdgcn_rsqf(var);  // SCALE / std
    const float c      = s * LOG2E;

    // stage the row pre-scaled (single LDS pass, raw came from registers)
    reinterpret_cast<float2*>(xs)[tid] = make_float2(v.x * c, v.y * c);

    // this thread's output element (all 8 waves cover the same 64 k's)
    const int   k   = blockIdx.x * KPB + lane;
    const float cxk = c * x[k];          // L2-hit re-read, one per thread

    __syncthreads();

    // acc = sum_j 1/(1 + 2^(cxk - c*x[j])), two independent quad chains
    float acc0 = 0.0f, acc1 = 0.0f;
    const int q0 = wave * (JCHUNK / 4);           // 32 quads per thread
    const float4* xs4 = reinterpret_cast<const float4*>(xs);
    #pragma unroll 4
    for (int q = q0; q < q0 + JCHUNK / 4; q += 2) {
        acc0 += quadSig(cxk, xs4[q]);
        acc1 += quadSig(cxk, xs4[q + 1]);
    }
    part[wave][lane] = acc0 + acc1;
    __syncthreads();

    if (tid < KPB) {
        float r = 0.f;
        #pragma unroll
        for (int w = 0; w < WAVES; ++w) r += part[w][tid];
        out[row * N + blockIdx.x * KPB + tid] = (r + 0.5f) * (1.0f / (float)N);
    }
}

extern "C" void kernel_launch(void* const* d_in, const int* in_sizes, int n_in,
                              void* d_out, int out_size, void* d_ws, size_t ws_size,
                              hipStream_t stream)
{
    const float* in  = (const float*)d_in[0];
    float*       out = (float*)d_out;

    const int total = in_sizes[0];      // B * N
    const int Brows = total / N;        // 64

    dim3 grid(N / KPB, Brows);          // (16, 64) = 1024 blocks x 512 thr
    softrank_kernel<<<grid, 512, 0, stream>>>(in, out);
}

// Round 5
// 15.034 us; speedup vs baseline: 1.2285x; 1.2285x over previous
//
#include <hip/hip_runtime.h>

// out[k] = (sum_j sigmoid(s*(x[j]-x[k])) + 0.5) / N,  s = SCALE/std(triu diff matrix)
// std closed form: var = (N*sum(x^2) - sum(x)^2 - S^2/N^2) / (N^2-1),
//                  S = sum_k x[k]*(2k - N + 1)
//
// R4: factored exponential. 2^(c*xk - c*xj) = Tk * Uj with Tk = 2^(c*xk)
// (1 exp2/thread) and Uj = 2^(-c*xj) staged in LDS (1024 exp2/row, amortized
// over 1024 outputs ~ free). Inner loop per element: mul + min + add +
// quad-rcp tree share -> 5 VALU + 0.26 trans = ~12 cy/elem issue vs 20 before.
// Overflow: |c*x| clamped to 60 -> factors <= 2^60, t <= 2^120 finite; the
// min(t,4096) bounds quad products <= 2^48. Sigma trunc err <= 2.4e-4.

constexpr int   N      = 1024;
constexpr int   KPB    = 64;          // outputs per block
constexpr int   WAVES  = 8;
constexpr int   JCHUNK = N / WAVES;   // 128 j's per wave
constexpr float SCALE  = 6.8f;
constexpr float LOG2E  = 1.4426950408889634f;

__device__ __forceinline__ float quadSig(float tk, float4 U)
{
    // t_i = Tk * Uj  (== 2^(c*(xk - xj)));  sum_i 1/(1+t_i) via one rcp
    float t0 = tk * U.x;
    float t1 = tk * U.y;
    float t2 = tk * U.z;
    float t3 = tk * U.w;
    t0 = fminf(t0, 4096.0f);
    t1 = fminf(t1, 4096.0f);
    t2 = fminf(t2, 4096.0f);
    t3 = fminf(t3, 4096.0f);
    const float a = t0 + 1.0f, b = t1 + 1.0f;
    const float c = t2 + 1.0f, d = t3 + 1.0f;
    const float ab  = a * b;
    const float cd  = c * d;
    const float num = (a + b) * cd + (c + d) * ab;   // 1/a+1/b+1/c+1/d = num/(ab*cd)
    return num * __builtin_amdgcn_rcpf(ab * cd);
}

__global__ __launch_bounds__(512) void softrank_kernel(
    const float* __restrict__ in, float* __restrict__ out)
{
    const int row  = blockIdx.y;
    const int tid  = threadIdx.x;
    const int lane = tid & 63;
    const int wave = tid >> 6;

    __shared__ float xs[N];           // Uj = 2^(-c*x[j])
    __shared__ float wred[WAVES][3];
    __shared__ float part[WAVES][KPB];

    const float* x = in + row * N;

    // 512 threads x float2 = 1024 elems; raw values stay in registers
    const float2 v = reinterpret_cast<const float2*>(x)[tid];

    // O(N) stats partials
    const int k0 = tid * 2;
    float psum = v.x + v.y;
    float psq  = v.x * v.x + v.y * v.y;
    float pw   = v.x * (float)(2 * k0       - (N - 1))
               + v.y * (float)(2 * (k0 + 1) - (N - 1));

    #pragma unroll
    for (int off = 32; off >= 1; off >>= 1) {
        psum += __shfl_down(psum, off, 64);
        psq  += __shfl_down(psq,  off, 64);
        pw   += __shfl_down(pw,   off, 64);
    }
    if (lane == 0) {
        wred[wave][0] = psum;
        wred[wave][1] = psq;
        wred[wave][2] = pw;
    }
    __syncthreads();

    float sum = 0.f, sq = 0.f, sw = 0.f;
    #pragma unroll
    for (int w = 0; w < WAVES; ++w) {
        sum += wred[w][0];
        sq  += wred[w][1];
        sw  += wred[w][2];
    }

    const float n2     = (float)N * (float)N;
    const float pairSq = (float)N * sq - sum * sum;
    const float var    = (pairSq - (sw * sw) / n2) / (n2 - 1.0f);
    const float s      = SCALE * __builtin_amdgcn_rsqf(var);  // SCALE / std
    const float c      = s * LOG2E;

    // stage Uj = 2^(-c*x[j]) (args clamped to +-60 for overflow safety)
    const float a0 = fminf(fmaxf(-c * v.x, -60.0f), 60.0f);
    const float a1 = fminf(fmaxf(-c * v.y, -60.0f), 60.0f);
    reinterpret_cast<float2*>(xs)[tid] =
        make_float2(__builtin_amdgcn_exp2f(a0), __builtin_amdgcn_exp2f(a1));

    // this thread's output element (all 8 waves cover the same 64 k's)
    const int   k   = blockIdx.x * KPB + lane;
    const float ak  = fminf(fmaxf(c * x[k], -60.0f), 60.0f);  // L2-hit reload
    const float tk  = __builtin_amdgcn_exp2f(ak);             // Tk = 2^(c*xk)

    __syncthreads();

    // acc = sum_j 1/(1 + Tk*Uj), two independent quad chains
    float acc0 = 0.0f, acc1 = 0.0f;
    const int q0 = wave * (JCHUNK / 4);           // 32 quads per thread
    const float4* xs4 = reinterpret_cast<const float4*>(xs);
    #pragma unroll 4
    for (int q = q0; q < q0 + JCHUNK / 4; q += 2) {
        acc0 += quadSig(tk, xs4[q]);
        acc1 += quadSig(tk, xs4[q + 1]);
    }
    part[wave][lane] = acc0 + acc1;
    __syncthreads();

    if (tid < KPB) {
        float r = 0.f;
        #pragma unroll
        for (int w = 0; w < WAVES; ++w) r += part[w][tid];
        out[row * N + blockIdx.x * KPB + tid] = (r + 0.5f) * (1.0f / (float)N);
    }
}

extern "C" void kernel_launch(void* const* d_in, const int* in_sizes, int n_in,
                              void* d_out, int out_size, void* d_ws, size_t ws_size,
                              hipStream_t stream)
{
    const float* in  = (const float*)d_in[0];
    float*       out = (float*)d_out;

    const int total = in_sizes[0];      // B * N
    const int Brows = total / N;        // 64

    dim3 grid(N / KPB, Brows);          // (16, 64) = 1024 blocks x 512 thr
    softrank_kernel<<<grid, 512, 0, stream>>>(in, out);
}

// Round 6
// 14.232 us; speedup vs baseline: 1.2978x; 1.0564x over previous
//
#include <hip/hip_runtime.h>

// out[k] = (sum_j sigmoid(s*(x[j]-x[k])) + 0.5) / N,  s = SCALE/std(triu diff matrix)
// std closed form: var = (N*sum(x^2) - sum(x)^2 - S^2/N^2) / (N^2-1),
//                  S = sum_k x[k]*(2k - N + 1)
//
// R5: fma-fold in the quad kernel. a = min(fma(tk,Uj,1), 4097) replaces
// mul->min->add (the old fmin between mul and add blocked fma fusion).
// 16 VALU + 1 trans per quad (40 cy issue) vs 20+1 (48 cy).
// Clamp semantics identical (a<=4097 == t<=4096); fma overflow -> inf ->
// min(inf,4097)=4097, finite. Quad products <= 2^48. Sigma trunc <= 2.4e-4.
// Model (5/5 rounds): dur = ~9.7us launch floor + issue cycles
// (VALU 2cy, trans 8cy per wave64 instr); LDS free (uniform broadcast reads).

constexpr int   N      = 1024;
constexpr int   KPB    = 64;          // outputs per block
constexpr int   WAVES  = 8;
constexpr int   JCHUNK = N / WAVES;   // 128 j's per wave
constexpr float SCALE  = 6.8f;
constexpr float LOG2E  = 1.4426950408889634f;

__device__ __forceinline__ float quadSig(float tk, float4 U)
{
    // a_i = 1 + tk*Uj  (tk*Uj == 2^(c*(xk - xj))), clamped; sum 1/a_i via one rcp
    float a = fminf(__builtin_fmaf(tk, U.x, 1.0f), 4097.0f);
    float b = fminf(__builtin_fmaf(tk, U.y, 1.0f), 4097.0f);
    float c = fminf(__builtin_fmaf(tk, U.z, 1.0f), 4097.0f);
    float d = fminf(__builtin_fmaf(tk, U.w, 1.0f), 4097.0f);
    const float ab  = a * b;
    const float cd  = c * d;
    const float num = (a + b) * cd + (c + d) * ab;   // 1/a+1/b+1/c+1/d = num/(ab*cd)
    return num * __builtin_amdgcn_rcpf(ab * cd);
}

__global__ __launch_bounds__(512) void softrank_kernel(
    const float* __restrict__ in, float* __restrict__ out)
{
    const int row  = blockIdx.y;
    const int tid  = threadIdx.x;
    const int lane = tid & 63;
    const int wave = tid >> 6;

    __shared__ float xs[N];           // Uj = 2^(-c*x[j])
    __shared__ float wred[WAVES][3];
    __shared__ float part[WAVES][KPB];

    const float* x = in + row * N;

    // 512 threads x float2 = 1024 elems; raw values stay in registers
    const float2 v = reinterpret_cast<const float2*>(x)[tid];

    // O(N) stats partials
    const int k0 = tid * 2;
    float psum = v.x + v.y;
    float psq  = v.x * v.x + v.y * v.y;
    float pw   = v.x * (float)(2 * k0       - (N - 1))
               + v.y * (float)(2 * (k0 + 1) - (N - 1));

    #pragma unroll
    for (int off = 32; off >= 1; off >>= 1) {
        psum += __shfl_down(psum, off, 64);
        psq  += __shfl_down(psq,  off, 64);
        pw   += __shfl_down(pw,   off, 64);
    }
    if (lane == 0) {
        wred[wave][0] = psum;
        wred[wave][1] = psq;
        wred[wave][2] = pw;
    }
    __syncthreads();

    float sum = 0.f, sq = 0.f, sw = 0.f;
    #pragma unroll
    for (int w = 0; w < WAVES; ++w) {
        sum += wred[w][0];
        sq  += wred[w][1];
        sw  += wred[w][2];
    }

    const float n2     = (float)N * (float)N;
    const float pairSq = (float)N * sq - sum * sum;
    const float var    = (pairSq - (sw * sw) / n2) / (n2 - 1.0f);
    const float s      = SCALE * __builtin_amdgcn_rsqf(var);  // SCALE / std
    const float c      = s * LOG2E;

    // stage Uj = 2^(-c*x[j]) (args clamped to +-60 for overflow safety)
    const float a0 = fminf(fmaxf(-c * v.x, -60.0f), 60.0f);
    const float a1 = fminf(fmaxf(-c * v.y, -60.0f), 60.0f);
    reinterpret_cast<float2*>(xs)[tid] =
        make_float2(__builtin_amdgcn_exp2f(a0), __builtin_amdgcn_exp2f(a1));

    // this thread's output element (all 8 waves cover the same 64 k's)
    const int   k   = blockIdx.x * KPB + lane;
    const float ak  = fminf(fmaxf(c * x[k], -60.0f), 60.0f);  // L2-hit reload
    const float tk  = __builtin_amdgcn_exp2f(ak);             // Tk = 2^(c*xk)

    __syncthreads();

    // acc = sum_j 1/(1 + Tk*Uj), two independent quad chains
    float acc0 = 0.0f, acc1 = 0.0f;
    const int q0 = wave * (JCHUNK / 4);           // 32 quads per thread
    const float4* xs4 = reinterpret_cast<const float4*>(xs);
    #pragma unroll 4
    for (int q = q0; q < q0 + JCHUNK / 4; q += 2) {
        acc0 += quadSig(tk, xs4[q]);
        acc1 += quadSig(tk, xs4[q + 1]);
    }
    part[wave][lane] = acc0 + acc1;
    __syncthreads();

    if (tid < KPB) {
        float r = 0.f;
        #pragma unroll
        for (int w = 0; w < WAVES; ++w) r += part[w][tid];
        out[row * N + blockIdx.x * KPB + tid] = (r + 0.5f) * (1.0f / (float)N);
    }
}

extern "C" void kernel_launch(void* const* d_in, const int* in_sizes, int n_in,
                              void* d_out, int out_size, void* d_ws, size_t ws_size,
                              hipStream_t stream)
{
    const float* in  = (const float*)d_in[0];
    float*       out = (float*)d_out;

    const int total = in_sizes[0];      // B * N
    const int Brows = total / N;        // 64

    dim3 grid(N / KPB, Brows);          // (16, 64) = 1024 blocks x 512 thr
    softrank_kernel<<<grid, 512, 0, stream>>>(in, out);
}

// Round 7
// 13.227 us; speedup vs baseline: 1.3964x; 1.0760x over previous
//
#include <hip/hip_runtime.h>

// out[k] = (sum_j sigmoid(s*(x[j]-x[k])) + 0.5) / N,  s = SCALE/std(triu diff matrix)
// std closed form: var = (N*sum(x^2) - sum(x)^2 - S^2/N^2) / (N^2-1),
//                  S = sum_k x[k]*(2k - N + 1)
//
// R6: symmetric-denominator sigmoid. sigma(s*(xj-xk)) = Vk/(Vk+Uj) with
// Vk = 2^(-c*xk), Uj = 2^(-c*xj). Inner loop per element is ONE v_add
// (no fma, no clamp); Vk hoists out of the quad-rcp tree entirely:
// out = Vk * sum quads[ num * rcp(den) ]. 12 VALU + 1 trans per quad
// (32 cy issue) vs 16+1 (40 cy) in R5.
// Overflow moved to staging: c*x clamped to +-30 -> V,U in [2^-30, 2^30],
// a = V+U <= 2^31, quad product <= 2^124 (finite), >= 2^-116 (no underflow).
// Tail-clamp error: ~2 elems/row beyond 3.1 sigma -> <~2e-3 in out (thr 2e-2).
// Model (6/6 rounds): dur = ~9.7us launch floor + issue cy (VALU 2, trans 8).

constexpr int   N      = 1024;
constexpr int   KPB    = 64;          // outputs per block
constexpr int   WAVES  = 8;
constexpr int   JCHUNK = N / WAVES;   // 128 j's per wave
constexpr float SCALE  = 6.8f;
constexpr float LOG2E  = 1.4426950408889634f;
constexpr float CLAMP  = 30.0f;       // max |c*x|; quad product <= 2^124

__device__ __forceinline__ float quadInv(float vk, float4 U)
{
    // sum_i 1/(vk + U_i) via one rcp
    const float a = vk + U.x;
    const float b = vk + U.y;
    const float c = vk + U.z;
    const float d = vk + U.w;
    const float ab  = a * b;
    const float cd  = c * d;
    const float num = (a + b) * cd + (c + d) * ab;   // 1/a+1/b+1/c+1/d = num/(ab*cd)
    return num * __builtin_amdgcn_rcpf(ab * cd);
}

__global__ __launch_bounds__(512) void softrank_kernel(
    const float* __restrict__ in, float* __restrict__ out)
{
    const int row  = blockIdx.y;
    const int tid  = threadIdx.x;
    const int lane = tid & 63;
    const int wave = tid >> 6;

    __shared__ float xs[N];           // Uj = 2^(-c*x[j]), clamped exponent
    __shared__ float wred[WAVES][3];
    __shared__ float part[WAVES][KPB];

    const float* x = in + row * N;

    // 512 threads x float2 = 1024 elems; raw values stay in registers
    const float2 v = reinterpret_cast<const float2*>(x)[tid];

    // O(N) stats partials
    const int k0 = tid * 2;
    float psum = v.x + v.y;
    float psq  = v.x * v.x + v.y * v.y;
    float pw   = v.x * (float)(2 * k0       - (N - 1))
               + v.y * (float)(2 * (k0 + 1) - (N - 1));

    #pragma unroll
    for (int off = 32; off >= 1; off >>= 1) {
        psum += __shfl_down(psum, off, 64);
        psq  += __shfl_down(psq,  off, 64);
        pw   += __shfl_down(pw,   off, 64);
    }
    if (lane == 0) {
        wred[wave][0] = psum;
        wred[wave][1] = psq;
        wred[wave][2] = pw;
    }
    __syncthreads();

    float sum = 0.f, sq = 0.f, sw = 0.f;
    #pragma unroll
    for (int w = 0; w < WAVES; ++w) {
        sum += wred[w][0];
        sq  += wred[w][1];
        sw  += wred[w][2];
    }

    const float n2     = (float)N * (float)N;
    const float pairSq = (float)N * sq - sum * sum;
    const float var    = (pairSq - (sw * sw) / n2) / (n2 - 1.0f);
    const float s      = SCALE * __builtin_amdgcn_rsqf(var);  // SCALE / std
    const float c      = s * LOG2E;

    // stage Uj = 2^(-c*x[j]), exponent clamped to +-CLAMP
    const float a0 = fminf(fmaxf(-c * v.x, -CLAMP), CLAMP);
    const float a1 = fminf(fmaxf(-c * v.y, -CLAMP), CLAMP);
    reinterpret_cast<float2*>(xs)[tid] =
        make_float2(__builtin_amdgcn_exp2f(a0), __builtin_amdgcn_exp2f(a1));

    // this thread's output element (all 8 waves cover the same 64 k's)
    const int   k   = blockIdx.x * KPB + lane;
    const float akx = fminf(fmaxf(-c * x[k], -CLAMP), CLAMP);  // L2-hit reload
    const float vk  = __builtin_amdgcn_exp2f(akx);             // Vk = 2^(-c*xk)

    __syncthreads();

    // acc = sum_j 1/(Vk + Uj), two independent quad chains; sigma-sum = Vk*acc
    float acc0 = 0.0f, acc1 = 0.0f;
    const int q0 = wave * (JCHUNK / 4);           // 32 quads per thread
    const float4* xs4 = reinterpret_cast<const float4*>(xs);
    #pragma unroll 4
    for (int q = q0; q < q0 + JCHUNK / 4; q += 2) {
        acc0 += quadInv(vk, xs4[q]);
        acc1 += quadInv(vk, xs4[q + 1]);
    }
    part[wave][lane] = vk * (acc0 + acc1);
    __syncthreads();

    if (tid < KPB) {
        float r = 0.f;
        #pragma unroll
        for (int w = 0; w < WAVES; ++w) r += part[w][tid];
        out[row * N + blockIdx.x * KPB + tid] = (r + 0.5f) * (1.0f / (float)N);
    }
}

extern "C" void kernel_launch(void* const* d_in, const int* in_sizes, int n_in,
                              void* d_out, int out_size, void* d_ws, size_t ws_size,
                              hipStream_t stream)
{
    const float* in  = (const float*)d_in[0];
    float*       out = (float*)d_out;

    const int total = in_sizes[0];      // B * N
    const int Brows = total / N;        // 64

    dim3 grid(N / KPB, Brows);          // (16, 64) = 1024 blocks x 512 thr
    softrank_kernel<<<grid, 512, 0, stream>>>(in, out);
}